// Round 5
// baseline (654.608 us; speedup 1.0000x reference)
//
#include <hip/hip_runtime.h>
#include <stdint.h>

typedef short bf16x8 __attribute__((ext_vector_type(8)));
typedef float f32x4  __attribute__((ext_vector_type(4)));

constexpr int BT = 4096;   // tokens
constexpr int DD = 1024;   // model dim
constexpr int OO = 1024;   // output dim
constexpr int EE = 8;      // experts
constexpr int HH = 4096;   // hidden dim
constexpr int SLOTS = 2 * BT;  // 8192

// ---- GEMM geometry: 128x128 tile, BK=32, ring-3, 3 blocks/CU ----
constexpr int BM = 128, BN = 128, BK = 32;
constexpr int A_USH = BM * BK;             // 4096 ushorts (8 KB)
constexpr int SLOT_USH = (BM + BN) * BK;   // 8192 ushorts (16 KB)
constexpr int MAXT = 72;                   // max 128-row m-tiles (worst case 71)
constexpr int G1_BLKS = 32 * MAXT;         // gemm1 slots in fusedB grid (2304)
constexpr int G2_BLKS = 8 * MAXT * 2;      // gemm2 grid (1152)

__device__ __forceinline__ unsigned short f2bf(float f) {
  unsigned u = __float_as_uint(f);
  u += 0x7fffu + ((u >> 16) & 1u);   // round-to-nearest-even
  return (unsigned short)(u >> 16);
}

// async 16B global->LDS. LDS dest is wave-uniform base; HW adds lane*16.
__device__ __forceinline__ void glds16(const unsigned short* g, unsigned short* l) {
  __builtin_amdgcn_global_load_lds(
      (const __attribute__((address_space(1))) void*)g,
      (__attribute__((address_space(3))) void*)l, 16, 0, 0);
}

// ------- transpose+convert body: src fp32 [e][R][C] -> dst bf16 [e][C][R] -------
__device__ __forceinline__ void cvt_body(const float* __restrict__ src,
                                         unsigned short* __restrict__ dst,
                                         int R, int C, int e, int r0, int c0, int t,
                                         unsigned short (*tile)[66]) {
  const float* s = src + (size_t)e * R * C;
  unsigned short* d = dst + (size_t)e * R * C;
#pragma unroll
  for (int p = 0; p < 4; ++p) {
    int ch = p * 256 + t;
    int rr = ch >> 4, cc = (ch & 15) << 2;
    float4 v = *(const float4*)&s[(size_t)(r0 + rr) * C + c0 + cc];
    unsigned lo = (unsigned)f2bf(v.x) | ((unsigned)f2bf(v.y) << 16);
    unsigned hi = (unsigned)f2bf(v.z) | ((unsigned)f2bf(v.w) << 16);
    *(uint2*)&tile[rr][cc] = make_uint2(lo, hi);
  }
  __syncthreads();
#pragma unroll
  for (int p = 0; p < 4; ++p) {
    int ch = p * 256 + t;
    int cc = ch >> 4, rr = (ch & 15) << 2;
    unsigned short v0 = tile[rr + 0][cc];
    unsigned short v1 = tile[rr + 1][cc];
    unsigned short v2 = tile[rr + 2][cc];
    unsigned short v3 = tile[rr + 3][cc];
    unsigned lo = (unsigned)v0 | ((unsigned)v1 << 16);
    unsigned hi = (unsigned)v2 | ((unsigned)v3 << 16);
    *(uint2*)&d[(size_t)(c0 + cc) * R + r0 + rr] = make_uint2(lo, hi);
  }
}

// ---------- fusedA: router (blocks 0..1023) + cvt(w1) (blocks 1024..9215) ----------
__global__ __launch_bounds__(256) void fusedA_k(const float* __restrict__ x,
                                                const float* __restrict__ gw,
                                                const float* __restrict__ gb,
                                                const float* __restrict__ w1,
                                                unsigned short* __restrict__ xb,
                                                int* __restrict__ cnt,
                                                int* __restrict__ list,
                                                float* __restrict__ rw,
                                                unsigned short* __restrict__ w1t) {
  __shared__ unsigned short tile[64][66];
  int bid = blockIdx.x;
  if (bid >= 1024) {  // cvt(w1): fp32 [e][1024][4096] -> bf16 [e][4096][1024]
    int idx = bid - 1024;
    int e = idx >> 10, rem = idx & 1023;
    int r0 = (rem & 15) << 6, c0 = (rem >> 4) << 6;
    cvt_body(w1, w1t, DD, HH, e, r0, c0, threadIdx.x, tile);
    return;
  }
  int wave = threadIdx.x >> 6, lane = threadIdx.x & 63;
  int b = bid * 4 + wave;
  const float* xrow = x + (size_t)b * DD;
  float acc[8];
#pragma unroll
  for (int e = 0; e < 8; ++e) acc[e] = 0.f;
#pragma unroll
  for (int i = 0; i < 4; ++i) {
    int d0 = i * 256 + lane * 4;
    float4 v = *(const float4*)&xrow[d0];
    unsigned lo = (unsigned)f2bf(v.x) | ((unsigned)f2bf(v.y) << 16);
    unsigned hi = (unsigned)f2bf(v.z) | ((unsigned)f2bf(v.w) << 16);
    *(uint2*)&xb[(size_t)b * DD + d0] = make_uint2(lo, hi);
    const float* g0 = &gw[(size_t)d0 * 8];
    float fv[4] = {v.x, v.y, v.z, v.w};
#pragma unroll
    for (int q = 0; q < 4; ++q) {
      float4 ga = *(const float4*)&g0[q * 8];
      float4 gc = *(const float4*)&g0[q * 8 + 4];
      acc[0] += fv[q] * ga.x; acc[1] += fv[q] * ga.y;
      acc[2] += fv[q] * ga.z; acc[3] += fv[q] * ga.w;
      acc[4] += fv[q] * gc.x; acc[5] += fv[q] * gc.y;
      acc[6] += fv[q] * gc.z; acc[7] += fv[q] * gc.w;
    }
  }
#pragma unroll
  for (int off = 32; off > 0; off >>= 1) {
#pragma unroll
    for (int e = 0; e < 8; ++e) acc[e] += __shfl_down(acc[e], off);
  }
  if (lane == 0) {
    float v[8];
#pragma unroll
    for (int e = 0; e < 8; ++e) v[e] = acc[e] + gb[e];
    int i0 = 0;
#pragma unroll
    for (int e = 1; e < 8; ++e) if (v[e] > v[i0]) i0 = e;
    int i1 = (i0 == 0) ? 1 : 0;
#pragma unroll
    for (int e = 0; e < 8; ++e) if (e != i0 && v[e] > v[i1]) i1 = e;
    float e1 = __expf(v[i1] - v[i0]);
    float inv = 1.0f / (1.0f + e1);
    int p0 = atomicAdd(&cnt[i0], 1);
    list[i0 * BT + p0] = 2 * b;     rw[2 * b]     = inv;
    int p1 = atomicAdd(&cnt[i1], 1);
    list[i1 * BT + p1] = 2 * b + 1; rw[2 * b + 1] = e1 * inv;
  }
}

// ---- tile map: (expert, m0, compacted_base) per 128-row tile ----
__global__ void tilemap_k(const int* __restrict__ cnt, int* __restrict__ tmap,
                          int* __restrict__ ntiles) {
  if (threadIdx.x == 0 && blockIdx.x == 0) {
    int t = 0, basewalk = 0;
    for (int e = 0; e < EE; ++e) {
      int c = cnt[e];
      for (int m0 = 0; m0 < c; m0 += BM) {
        tmap[4 * t] = e; tmap[4 * t + 1] = m0; tmap[4 * t + 2] = basewalk + m0; ++t;
      }
      basewalk += c;
    }
    *ntiles = t;
  }
}

// standalone cvt (tight-ws fallback only)
__global__ __launch_bounds__(256) void cvt_t_k(const float* __restrict__ src,
                                               unsigned short* __restrict__ dst,
                                               int R, int C) {
  __shared__ unsigned short tile[64][66];
  cvt_body(src, dst, R, C, blockIdx.z, blockIdx.x << 6, blockIdx.y << 6,
           threadIdx.x, tile);
}

// =====================================================================
// fusedB: GEMM1 (blocks 0..G1_BLKS-1) + cvt(w2) (blocks G1_BLKS..+8191).
// GEMM1: hc[base+row] = relu(x[tok] @ w1[e] + b1[e]), compacted layout.
// 128x128 tile, BK=32, ring-3 counted-vmcnt, XOR chunk swizzle, 3 blk/CU.
// XCD-aware swizzle (T1): q = f&7 is the XCD; within an XCD, the 32
// n-tiles of one m-tile run consecutively -> A-panel fetched once per
// XCD and L2-resident for the other 31 reads. m-tiles interleave across
// XCDs (mslot = (k>>5)*8 + q, bijective over [0,72)).
// =====================================================================
__global__ __launch_bounds__(256, 3) void fusedB_k(const unsigned short* __restrict__ xb,
                                                   const unsigned short* __restrict__ w1t,
                                                   const float* __restrict__ b1,
                                                   const int* __restrict__ cnt,
                                                   const int* __restrict__ list,
                                                   const int* __restrict__ tmap,
                                                   const int* __restrict__ ntiles,
                                                   unsigned short* __restrict__ hc,
                                                   const float* __restrict__ w2,
                                                   unsigned short* __restrict__ w2t) {
  __shared__ __align__(16) unsigned short lds[3 * SLOT_USH];  // 48 KB
  __shared__ int slotbuf[BM];
  int bid = blockIdx.x;
  if (bid >= G1_BLKS) {  // cvt(w2): fp32 [e][4096][1024] -> bf16 [e][1024][4096]
    int idx = bid - G1_BLKS;
    int e = idx >> 10, rem = idx & 1023;
    int r0 = (rem & 63) << 6, c0 = (rem >> 6) << 6;
    cvt_body(w2, w2t, HH, OO, e, r0, c0, threadIdx.x,
             (unsigned short (*)[66])lds);
    return;
  }
  // XCD swizzle: f = 8k+q -> XCD q; n fastest within XCD, m interleaved.
  int q = bid & 7, kk = bid >> 3;          // kk in [0,288)
  int n0 = (kk & 31) * BN;                 // 32 n-tiles, consecutive on one XCD
  int ti = (kk >> 5) * 8 + q;              // [0,72) bijective
  if (ti >= *ntiles) return;
  int e = tmap[4 * ti], m0 = tmap[4 * ti + 1], base = tmap[4 * ti + 2];
  int cnt_e = cnt[e];

  int t = threadIdx.x;
  if (t < BM) {
    int r = m0 + t;
    slotbuf[t] = list[e * BT + (r < cnt_e ? r : 0)];
  }
  __syncthreads();

  int w = t >> 6, l = t & 63, lm = l & 15, lq = l >> 4;
  int wm = (w >> 1) * 64, wn = (w & 1) * 64;

  // staging: 4 x 16B per thread per K-tile (A j=0/1, B j=0/1); wave w covers
  // rows [w*32, w*32+32). Inverse swizzle on the GLOBAL source chunk.
  const unsigned short* aS[2];
  const unsigned short* bS[2];
  int dA[2], dB[2];
#pragma unroll
  for (int j = 0; j < 2; ++j) {
    int row = w * 32 + j * 16 + (l >> 2);
    int sch = ((l & 3) ^ ((row >> 1) & 3)) * 8;
    aS[j] = xb + (size_t)(slotbuf[row] >> 1) * DD + sch;
    bS[j] = w1t + (size_t)e * HH * DD + (size_t)(n0 + row) * DD + sch;
    dA[j] = w * 1024 + j * 512;
    dB[j] = A_USH + w * 1024 + j * 512;
  }

  // fragment read offsets with matching swizzle (2-way -> conflict-free)
  int xs = (lq ^ ((lm >> 1) & 3)) * 8;
  int afo[4], bfo[4];
#pragma unroll
  for (int mi = 0; mi < 4; ++mi) afo[mi] = (wm + mi * 16 + lm) * BK + xs;
#pragma unroll
  for (int ni = 0; ni < 4; ++ni) bfo[ni] = A_USH + (wn + ni * 16 + lm) * BK + xs;

  f32x4 acc[4][4];
#pragma unroll
  for (int mi = 0; mi < 4; ++mi)
#pragma unroll
    for (int ni = 0; ni < 4; ++ni) acc[mi][ni] = f32x4{0.f, 0.f, 0.f, 0.f};

  constexpr int NT = DD / BK;  // 32

  // ring-3 prologue: stage tiles 0 (slot0) and 1 (slot1)
#pragma unroll
  for (int p = 0; p < 2; ++p) {
    unsigned short* Lb = lds + p * SLOT_USH;
    glds16(aS[0] + p * BK, Lb + dA[0]);
    glds16(aS[1] + p * BK, Lb + dA[1]);
    glds16(bS[0] + p * BK, Lb + dB[0]);
    glds16(bS[1] + p * BK, Lb + dB[1]);
  }
  asm volatile("s_waitcnt vmcnt(4)" ::: "memory");  // tile 0 landed
  __builtin_amdgcn_s_barrier();
  asm volatile("" ::: "memory");

  int sc = 0, ss = 2;
  for (int tt = 0; tt < NT; ++tt) {
    {  // stage tile tt+2 (branchless clamped tail keeps vmcnt exact)
      int ts = tt + 2;
      int ko = (ts < NT ? ts : NT - 1) * BK;
      unsigned short* Lb = lds + ss * SLOT_USH;
      glds16(aS[0] + ko, Lb + dA[0]);
      glds16(aS[1] + ko, Lb + dA[1]);
      glds16(bS[0] + ko, Lb + dB[0]);
      glds16(bS[1] + ko, Lb + dB[1]);
    }
    const unsigned short* Lc = lds + sc * SLOT_USH;
    bf16x8 af[4], bf[4];
#pragma unroll
    for (int mi = 0; mi < 4; ++mi) af[mi] = *(const bf16x8*)&Lc[afo[mi]];
#pragma unroll
    for (int ni = 0; ni < 4; ++ni) bf[ni] = *(const bf16x8*)&Lc[bfo[ni]];
    __builtin_amdgcn_s_setprio(1);
#pragma unroll
    for (int mi = 0; mi < 4; ++mi)
#pragma unroll
      for (int ni = 0; ni < 4; ++ni)
        acc[mi][ni] = __builtin_amdgcn_mfma_f32_16x16x32_bf16(af[mi], bf[ni], acc[mi][ni], 0, 0, 0);
    __builtin_amdgcn_s_setprio(0);
    asm volatile("s_waitcnt vmcnt(4)" ::: "memory");  // tile tt+1 landed
    __builtin_amdgcn_s_barrier();
    asm volatile("" ::: "memory");
    if (++sc == 3) sc = 0;
    if (++ss == 3) ss = 0;
  }

  // epilogue: drain, then LDS-transpose -> coalesced 16B stores
  asm volatile("s_waitcnt vmcnt(0)" ::: "memory");
  __builtin_amdgcn_s_barrier();
  asm volatile("" ::: "memory");
  unsigned short* cb = lds + w * 4096;  // 64x64 bf16 per wave (8 KB)
  float bias[4];
#pragma unroll
  for (int ni = 0; ni < 4; ++ni) bias[ni] = b1[e * HH + n0 + wn + ni * 16 + lm];
#pragma unroll
  for (int mi = 0; mi < 4; ++mi)
#pragma unroll
    for (int ni = 0; ni < 4; ++ni)
#pragma unroll
      for (int r = 0; r < 4; ++r)
        cb[(mi * 16 + lq * 4 + r) * 64 + ni * 16 + lm] =
            f2bf(fmaxf(acc[mi][ni][r] + bias[ni], 0.0f));
  asm volatile("s_waitcnt lgkmcnt(0)" ::: "memory");
#pragma unroll
  for (int it = 0; it < 8; ++it) {
    int rr = it * 8 + (l >> 3), chk = l & 7;
    int grow = wm + rr;
    if (m0 + grow < cnt_e) {
      uint4 v = *(const uint4*)&cb[rr * 64 + chk * 8];
      *(uint4*)&hc[(size_t)(base + grow) * HH + n0 + wn + chk * 8] = v;
    }
  }
}

// =====================================================================
// GEMM2: y[z][slot] = rw*(hc_rows @ w2[e] + b2[e] [z==0]); same pipeline.
// 1-D grid G2_BLKS = 8n x 72m x 2z, XCD-swizzled: q = f&7 is the XCD;
// the 8 n-tiles of one (m,z) run consecutively on one XCD (A L2-reuse);
// (m,z) slots interleave across XCDs: mz = (k>>3)*8 + q, bijective [0,144).
// =====================================================================
__global__ __launch_bounds__(256, 3) void gemm2_k(const unsigned short* __restrict__ hc,
                                                  const unsigned short* __restrict__ w2t,
                                                  const float* __restrict__ b2,
                                                  const int* __restrict__ cnt,
                                                  const int* __restrict__ list,
                                                  const int* __restrict__ tmap,
                                                  const int* __restrict__ ntiles,
                                                  const float* __restrict__ rw,
                                                  float* __restrict__ ybuf,
                                                  float* __restrict__ out) {
  int q = blockIdx.x & 7, kk = blockIdx.x >> 3;  // kk in [0,144)
  int n0 = (kk & 7) * BN;                        // 8 n-tiles per (m,z)
  int mz = (kk >> 3) * 8 + q;                    // [0,144) bijective
  int z = mz / MAXT;
  int ti = mz % MAXT;
  if (ti >= *ntiles) return;
  int e = tmap[4 * ti], m0 = tmap[4 * ti + 1], base = tmap[4 * ti + 2];
  int cnt_e = cnt[e];
  int kb0 = z * (HH / 2);
  constexpr int NT = (HH / 2) / BK;  // 64

  __shared__ __align__(16) unsigned short lds[3 * SLOT_USH];
  __shared__ int slotbuf[BM];
  __shared__ float rwbuf[BM];

  int t = threadIdx.x;
  if (t < BM) {
    int r = m0 + t;
    int s_ = list[e * BT + (r < cnt_e ? r : 0)];
    slotbuf[t] = s_;
    rwbuf[t] = rw[s_];
  }
  __syncthreads();

  int w = t >> 6, l = t & 63, lm = l & 15, lq = l >> 4;
  int wm = (w >> 1) * 64, wn = (w & 1) * 64;

  const unsigned short* aS[2];
  const unsigned short* bS[2];
  int dA[2], dB[2];
#pragma unroll
  for (int j = 0; j < 2; ++j) {
    int row = w * 32 + j * 16 + (l >> 2);
    int sch = ((l & 3) ^ ((row >> 1) & 3)) * 8;
    int gr = base + row; if (gr > SLOTS - 1) gr = SLOTS - 1;  // clamp padded rows
    aS[j] = hc + (size_t)gr * HH + kb0 + sch;
    bS[j] = w2t + (size_t)e * OO * HH + (size_t)(n0 + row) * HH + kb0 + sch;
    dA[j] = w * 1024 + j * 512;
    dB[j] = A_USH + w * 1024 + j * 512;
  }

  int xs = (lq ^ ((lm >> 1) & 3)) * 8;
  int afo[4], bfo[4];
#pragma unroll
  for (int mi = 0; mi < 4; ++mi) afo[mi] = (wm + mi * 16 + lm) * BK + xs;
#pragma unroll
  for (int ni = 0; ni < 4; ++ni) bfo[ni] = A_USH + (wn + ni * 16 + lm) * BK + xs;

  f32x4 acc[4][4];
#pragma unroll
  for (int mi = 0; mi < 4; ++mi)
#pragma unroll
    for (int ni = 0; ni < 4; ++ni) acc[mi][ni] = f32x4{0.f, 0.f, 0.f, 0.f};

#pragma unroll
  for (int p = 0; p < 2; ++p) {
    unsigned short* Lb = lds + p * SLOT_USH;
    glds16(aS[0] + p * BK, Lb + dA[0]);
    glds16(aS[1] + p * BK, Lb + dA[1]);
    glds16(bS[0] + p * BK, Lb + dB[0]);
    glds16(bS[1] + p * BK, Lb + dB[1]);
  }
  asm volatile("s_waitcnt vmcnt(4)" ::: "memory");
  __builtin_amdgcn_s_barrier();
  asm volatile("" ::: "memory");

  int sc = 0, ss = 2;
  for (int tt = 0; tt < NT; ++tt) {
    {
      int ts = tt + 2;
      int ko = (ts < NT ? ts : NT - 1) * BK;
      unsigned short* Lb = lds + ss * SLOT_USH;
      glds16(aS[0] + ko, Lb + dA[0]);
      glds16(aS[1] + ko, Lb + dA[1]);
      glds16(bS[0] + ko, Lb + dB[0]);
      glds16(bS[1] + ko, Lb + dB[1]);
    }
    const unsigned short* Lc = lds + sc * SLOT_USH;
    bf16x8 af[4], bf[4];
#pragma unroll
    for (int mi = 0; mi < 4; ++mi) af[mi] = *(const bf16x8*)&Lc[afo[mi]];
#pragma unroll
    for (int ni = 0; ni < 4; ++ni) bf[ni] = *(const bf16x8*)&Lc[bfo[ni]];
    __builtin_amdgcn_s_setprio(1);
#pragma unroll
    for (int mi = 0; mi < 4; ++mi)
#pragma unroll
      for (int ni = 0; ni < 4; ++ni)
        acc[mi][ni] = __builtin_amdgcn_mfma_f32_16x16x32_bf16(af[mi], bf[ni], acc[mi][ni], 0, 0, 0);
    __builtin_amdgcn_s_setprio(0);
    asm volatile("s_waitcnt vmcnt(4)" ::: "memory");
    __builtin_amdgcn_s_barrier();
    asm volatile("" ::: "memory");
    if (++sc == 3) sc = 0;
    if (++ss == 3) ss = 0;
  }
  asm volatile("s_waitcnt vmcnt(0)" ::: "memory");  // drain clamped tail loads

  bool addb = (z == 0);
  size_t ybase = (size_t)z * SLOTS;
#pragma unroll
  for (int ni = 0; ni < 4; ++ni) {
    int ncol = n0 + wn + ni * 16 + lm;
    float bias = addb ? b2[e * OO + ncol] : 0.0f;
#pragma unroll
    for (int mi = 0; mi < 4; ++mi)
#pragma unroll
      for (int r = 0; r < 4; ++r) {
        int lrow = wm + mi * 16 + lq * 4 + r;
        if (m0 + lrow < cnt_e) {
          float v = (acc[mi][ni][r] + bias) * rwbuf[lrow];
          int slot = slotbuf[lrow];
          if (ybuf) ybuf[(ybase + slot) * OO + ncol] = v;
          else      atomicAdd(&out[(size_t)(slot >> 1) * OO + ncol], v);
        }
      }
  }
}

// ---- combine: out[b] = sum_z (y[z][2b] + y[z][2b+1]) ----
__global__ __launch_bounds__(256) void combine_k(const float* __restrict__ y,
                                                 float* __restrict__ out, int nz) {
  int i = blockIdx.x * 256 + threadIdx.x;
  int b = i >> 8, c = i & 255;
  f32x4 acc = {0.f, 0.f, 0.f, 0.f};
  for (int z = 0; z < nz; ++z) {
#pragma unroll
    for (int k = 0; k < 2; ++k) {
      const float4 v = *(const float4*)&y[((size_t)z * SLOTS + 2 * b + k) * OO + c * 4];
      acc[0] += v.x; acc[1] += v.y; acc[2] += v.z; acc[3] += v.w;
    }
  }
  *(f32x4*)&out[(size_t)b * OO + c * 4] = acc;
}

extern "C" void kernel_launch(void* const* d_in, const int* in_sizes, int n_in,
                              void* d_out, int out_size, void* d_ws, size_t ws_size,
                              hipStream_t stream) {
  const float* x  = (const float*)d_in[0];
  const float* gw = (const float*)d_in[1];
  const float* gb = (const float*)d_in[2];
  const float* w1 = (const float*)d_in[3];
  const float* b1 = (const float*)d_in[4];
  const float* w2 = (const float*)d_in[5];
  const float* b2 = (const float*)d_in[6];
  float* out = (float*)d_out;
  char* ws = (char*)d_ws;

  int*            cnt    = (int*)(ws);                          // 32 B
  int*            ntiles = (int*)(ws + 64);
  int*            tmap   = (int*)(ws + 128);                    // 72*16 B
  float*          rw     = (float*)(ws + 4096);                 // 32 KB
  int*            list   = (int*)(ws + (64u << 10));            // 128 KB
  unsigned short* xb     = (unsigned short*)(ws + (1u  << 20)); // 8 MB
  unsigned short* w1t    = (unsigned short*)(ws + (9u  << 20)); // 64 MB

  bool roomy = ws_size >= (201u << 20);
  hipMemsetAsync(cnt, 0, 64, stream);

  if (roomy) {
    // w2t gets its own region so cvt(w2) overlaps gemm1; ybuf aliases w1t
    // (w1t dead after fusedB; ybuf live only gemm2->combine).
    unsigned short* w2t = (unsigned short*)(ws + (73u  << 20));  // 64 MB
    unsigned short* hc  = (unsigned short*)(ws + (137u << 20));  // 64 MB
    float*          ybuf = (float*)(ws + (9u << 20));            // alias w1t

    fusedA_k<<<1024 + 8192, 256, 0, stream>>>(x, gw, gb, w1, xb, cnt, list, rw, w1t);
    tilemap_k<<<1, 64, 0, stream>>>(cnt, tmap, ntiles);
    fusedB_k<<<G1_BLKS + 8192, 256, 0, stream>>>(xb, w1t, b1, cnt, list, tmap, ntiles,
                                                 hc, w2, w2t);
    gemm2_k<<<G2_BLKS, 256, 0, stream>>>(hc, w2t, b2, cnt, list, tmap,
                                         ntiles, rw, ybuf, out);
    combine_k<<<BT * OO / 1024, 256, 0, stream>>>(ybuf, out, 2);
  } else {
    // tight fallback: serial cvt(w2) overwrites w1t region; atomic gemm2.
    if (ws_size < (137u << 20)) return;
    unsigned short* w2t = w1t;
    unsigned short* hc  = (unsigned short*)(ws + (73u << 20));
    hipMemsetAsync(out, 0, (size_t)BT * OO * sizeof(float), stream);
    fusedA_k<<<1024 + 8192, 256, 0, stream>>>(x, gw, gb, w1, xb, cnt, list, rw, w1t);
    tilemap_k<<<1, 64, 0, stream>>>(cnt, tmap, ntiles);
    fusedB_k<<<G1_BLKS, 256, 0, stream>>>(xb, w1t, b1, cnt, list, tmap, ntiles,
                                          hc, w2, w2t);
    cvt_t_k<<<dim3(HH / 64, OO / 64, EE), 256, 0, stream>>>(w2, w2t, HH, OO);
    gemm2_k<<<G2_BLKS, 256, 0, stream>>>(hc, w2t, b2, cnt, list, tmap,
                                         ntiles, rw, nullptr, out);
  }
}

// Round 7
// 642.803 us; speedup vs baseline: 1.0184x; 1.0184x over previous
//
#include <hip/hip_runtime.h>
#include <stdint.h>

typedef short bf16x8 __attribute__((ext_vector_type(8)));
typedef float f32x4  __attribute__((ext_vector_type(4)));

constexpr int BT = 4096;   // tokens
constexpr int DD = 1024;   // model dim
constexpr int OO = 1024;   // output dim
constexpr int EE = 8;      // experts
constexpr int HH = 4096;   // hidden dim
constexpr int SLOTS = 2 * BT;  // 8192

// ---- GEMM geometry: 128x128 tile, BK=32, ring-3, 3 blocks/CU ----
constexpr int BM = 128, BN = 128, BK = 32;
constexpr int A_USH = BM * BK;             // 4096 ushorts (8 KB)
constexpr int SLOT_USH = (BM + BN) * BK;   // 8192 ushorts (16 KB)
constexpr int MTS = 32;                    // m-tile slots/expert (covers 4096 tok worst case)
// gemm1: XCD q=f&7 <-> expert q; on-XCD order m-fastest within n-column.
constexpr int G1_BLKS = 8 * 32 * MTS;      // 8192
// gemm2: XCD q <-> expert q; z in {0,1} sequential; m-fastest within n-column.
constexpr int G2_BLKS = 8 * 2 * 8 * MTS;   // 4096

__device__ __forceinline__ unsigned short f2bf(float f) {
  unsigned u = __float_as_uint(f);
  u += 0x7fffu + ((u >> 16) & 1u);   // round-to-nearest-even
  return (unsigned short)(u >> 16);
}

// async 16B global->LDS. LDS dest is wave-uniform base; HW adds lane*16.
__device__ __forceinline__ void glds16(const unsigned short* g, unsigned short* l) {
  __builtin_amdgcn_global_load_lds(
      (const __attribute__((address_space(1))) void*)g,
      (__attribute__((address_space(3))) void*)l, 16, 0, 0);
}

// ------- transpose+convert body: src fp32 [e][R][C] -> dst bf16 [e][C][R] -------
__device__ __forceinline__ void cvt_body(const float* __restrict__ src,
                                         unsigned short* __restrict__ dst,
                                         int R, int C, int e, int r0, int c0, int t,
                                         unsigned short (*tile)[66]) {
  const float* s = src + (size_t)e * R * C;
  unsigned short* d = dst + (size_t)e * R * C;
#pragma unroll
  for (int p = 0; p < 4; ++p) {
    int ch = p * 256 + t;
    int rr = ch >> 4, cc = (ch & 15) << 2;
    float4 v = *(const float4*)&s[(size_t)(r0 + rr) * C + c0 + cc];
    unsigned lo = (unsigned)f2bf(v.x) | ((unsigned)f2bf(v.y) << 16);
    unsigned hi = (unsigned)f2bf(v.z) | ((unsigned)f2bf(v.w) << 16);
    *(uint2*)&tile[rr][cc] = make_uint2(lo, hi);
  }
  __syncthreads();
#pragma unroll
  for (int p = 0; p < 4; ++p) {
    int ch = p * 256 + t;
    int cc = ch >> 4, rr = (ch & 15) << 2;
    unsigned short v0 = tile[rr + 0][cc];
    unsigned short v1 = tile[rr + 1][cc];
    unsigned short v2 = tile[rr + 2][cc];
    unsigned short v3 = tile[rr + 3][cc];
    unsigned lo = (unsigned)v0 | ((unsigned)v1 << 16);
    unsigned hi = (unsigned)v2 | ((unsigned)v3 << 16);
    *(uint2*)&d[(size_t)(c0 + cc) * R + r0 + rr] = make_uint2(lo, hi);
  }
}

// ---------- fusedA: router (blocks 0..1023) + cvt(w1) (blocks 1024..9215) ----------
__global__ __launch_bounds__(256) void fusedA_k(const float* __restrict__ x,
                                                const float* __restrict__ gw,
                                                const float* __restrict__ gb,
                                                const float* __restrict__ w1,
                                                unsigned short* __restrict__ xb,
                                                int* __restrict__ cnt,
                                                int* __restrict__ list,
                                                float* __restrict__ rw,
                                                unsigned short* __restrict__ w1t) {
  __shared__ unsigned short tile[64][66];
  int bid = blockIdx.x;
  if (bid >= 1024) {  // cvt(w1): fp32 [e][1024][4096] -> bf16 [e][4096][1024]
    int idx = bid - 1024;
    int e = idx >> 10, rem = idx & 1023;
    int r0 = (rem & 15) << 6, c0 = (rem >> 4) << 6;
    cvt_body(w1, w1t, DD, HH, e, r0, c0, threadIdx.x, tile);
    return;
  }
  int wave = threadIdx.x >> 6, lane = threadIdx.x & 63;
  int b = bid * 4 + wave;
  const float* xrow = x + (size_t)b * DD;
  float acc[8];
#pragma unroll
  for (int e = 0; e < 8; ++e) acc[e] = 0.f;
#pragma unroll
  for (int i = 0; i < 4; ++i) {
    int d0 = i * 256 + lane * 4;
    float4 v = *(const float4*)&xrow[d0];
    unsigned lo = (unsigned)f2bf(v.x) | ((unsigned)f2bf(v.y) << 16);
    unsigned hi = (unsigned)f2bf(v.z) | ((unsigned)f2bf(v.w) << 16);
    *(uint2*)&xb[(size_t)b * DD + d0] = make_uint2(lo, hi);
    const float* g0 = &gw[(size_t)d0 * 8];
    float fv[4] = {v.x, v.y, v.z, v.w};
#pragma unroll
    for (int q = 0; q < 4; ++q) {
      float4 ga = *(const float4*)&g0[q * 8];
      float4 gc = *(const float4*)&g0[q * 8 + 4];
      acc[0] += fv[q] * ga.x; acc[1] += fv[q] * ga.y;
      acc[2] += fv[q] * ga.z; acc[3] += fv[q] * ga.w;
      acc[4] += fv[q] * gc.x; acc[5] += fv[q] * gc.y;
      acc[6] += fv[q] * gc.z; acc[7] += fv[q] * gc.w;
    }
  }
#pragma unroll
  for (int off = 32; off > 0; off >>= 1) {
#pragma unroll
    for (int e = 0; e < 8; ++e) acc[e] += __shfl_down(acc[e], off);
  }
  if (lane == 0) {
    float v[8];
#pragma unroll
    for (int e = 0; e < 8; ++e) v[e] = acc[e] + gb[e];
    int i0 = 0;
#pragma unroll
    for (int e = 1; e < 8; ++e) if (v[e] > v[i0]) i0 = e;
    int i1 = (i0 == 0) ? 1 : 0;
#pragma unroll
    for (int e = 0; e < 8; ++e) if (e != i0 && v[e] > v[i1]) i1 = e;
    float e1 = __expf(v[i1] - v[i0]);
    float inv = 1.0f / (1.0f + e1);
    int p0 = atomicAdd(&cnt[i0], 1);
    list[i0 * BT + p0] = 2 * b;     rw[2 * b]     = inv;
    int p1 = atomicAdd(&cnt[i1], 1);
    list[i1 * BT + p1] = 2 * b + 1; rw[2 * b + 1] = e1 * inv;
  }
}

// ---- tile map: (expert, m0, compacted_base) per 128-row tile + per-expert prefix ----
__global__ void tilemap_k(const int* __restrict__ cnt, int* __restrict__ tmap,
                          int* __restrict__ ntiles, int* __restrict__ tstart) {
  if (threadIdx.x == 0 && blockIdx.x == 0) {
    int t = 0, basewalk = 0;
    for (int e = 0; e < EE; ++e) {
      tstart[e] = t;
      int c = cnt[e];
      for (int m0 = 0; m0 < c; m0 += BM) {
        tmap[4 * t] = e; tmap[4 * t + 1] = m0; tmap[4 * t + 2] = basewalk + m0; ++t;
      }
      basewalk += c;
    }
    tstart[EE] = t;
    *ntiles = t;
  }
}

// standalone cvt (tight-ws fallback only)
__global__ __launch_bounds__(256) void cvt_t_k(const float* __restrict__ src,
                                               unsigned short* __restrict__ dst,
                                               int R, int C) {
  __shared__ unsigned short tile[64][66];
  cvt_body(src, dst, R, C, blockIdx.z, blockIdx.x << 6, blockIdx.y << 6,
           threadIdx.x, tile);
}

// =====================================================================
// fusedB: GEMM1 (blocks 0..G1_BLKS-1) + cvt(w2) (blocks G1_BLKS..+8191).
// GEMM1: hc[base+row] = relu(x[tok] @ w1[e] + b1[e]), compacted layout.
// 128x128 tile, BK=32, ring-3 counted-vmcnt, XOR chunk swizzle, 3 blk/CU.
// Locality: XCD q = f&7 <-> expert q. On-XCD slot r = f>>3 runs m-fastest
// (mts inner, nt outer): a whole n-column (~8 m-tiles) shares one 0.25 MB
// B panel (L2-hit after first), and the expert's full A-set (~2 MB of xb
// rows) + B column fit the 4 MB XCD L2 across columns.
// =====================================================================
__global__ __launch_bounds__(256, 3) void fusedB_k(const unsigned short* __restrict__ xb,
                                                   const unsigned short* __restrict__ w1t,
                                                   const float* __restrict__ b1,
                                                   const int* __restrict__ cnt,
                                                   const int* __restrict__ list,
                                                   const int* __restrict__ tmap,
                                                   const int* __restrict__ tstart,
                                                   unsigned short* __restrict__ hc,
                                                   const float* __restrict__ w2,
                                                   unsigned short* __restrict__ w2t) {
  __shared__ __align__(16) unsigned short lds[3 * SLOT_USH];  // 48 KB
  __shared__ int slotbuf[BM];
  int bid = blockIdx.x;
  if (bid >= G1_BLKS) {  // cvt(w2): fp32 [e][4096][1024] -> bf16 [e][1024][4096]
    int idx = bid - G1_BLKS;
    int e = idx >> 10, rem = idx & 1023;
    int r0 = (rem & 63) << 6, c0 = (rem >> 6) << 6;
    cvt_body(w2, w2t, HH, OO, e, r0, c0, threadIdx.x,
             (unsigned short (*)[66])lds);
    return;
  }
  // expert<->XCD affinity decode
  int q = bid & 7, r = bid >> 3;
  int mts = r & (MTS - 1), nt = r >> 5;    // m-fastest within n-column
  int tc0 = tstart[q];
  if (tc0 + mts >= tstart[q + 1]) return;  // beyond this expert's m-tiles
  int ti = tc0 + mts;
  int e = tmap[4 * ti], m0 = tmap[4 * ti + 1], base = tmap[4 * ti + 2];
  int cnt_e = cnt[e];
  int n0 = nt * BN;

  int t = threadIdx.x;
  if (t < BM) {
    int rr = m0 + t;
    slotbuf[t] = list[e * BT + (rr < cnt_e ? rr : 0)];
  }
  __syncthreads();

  int w = t >> 6, l = t & 63, lm = l & 15, lq = l >> 4;
  int wm = (w >> 1) * 64, wn = (w & 1) * 64;

  // staging: 4 x 16B per thread per K-tile (A j=0/1, B j=0/1); wave w covers
  // rows [w*32, w*32+32). Inverse swizzle on the GLOBAL source chunk.
  const unsigned short* aS[2];
  const unsigned short* bS[2];
  int dA[2], dB[2];
#pragma unroll
  for (int j = 0; j < 2; ++j) {
    int row = w * 32 + j * 16 + (l >> 2);
    int sch = ((l & 3) ^ ((row >> 1) & 3)) * 8;
    aS[j] = xb + (size_t)(slotbuf[row] >> 1) * DD + sch;
    bS[j] = w1t + (size_t)e * HH * DD + (size_t)(n0 + row) * DD + sch;
    dA[j] = w * 1024 + j * 512;
    dB[j] = A_USH + w * 1024 + j * 512;
  }

  // fragment read offsets with matching swizzle (2-way -> conflict-free)
  int xs = (lq ^ ((lm >> 1) & 3)) * 8;
  int afo[4], bfo[4];
#pragma unroll
  for (int mi = 0; mi < 4; ++mi) afo[mi] = (wm + mi * 16 + lm) * BK + xs;
#pragma unroll
  for (int ni = 0; ni < 4; ++ni) bfo[ni] = A_USH + (wn + ni * 16 + lm) * BK + xs;

  f32x4 acc[4][4];
#pragma unroll
  for (int mi = 0; mi < 4; ++mi)
#pragma unroll
    for (int ni = 0; ni < 4; ++ni) acc[mi][ni] = f32x4{0.f, 0.f, 0.f, 0.f};

  constexpr int NT = DD / BK;  // 32

  // ring-3 prologue: stage tiles 0 (slot0) and 1 (slot1)
#pragma unroll
  for (int p = 0; p < 2; ++p) {
    unsigned short* Lb = lds + p * SLOT_USH;
    glds16(aS[0] + p * BK, Lb + dA[0]);
    glds16(aS[1] + p * BK, Lb + dA[1]);
    glds16(bS[0] + p * BK, Lb + dB[0]);
    glds16(bS[1] + p * BK, Lb + dB[1]);
  }
  asm volatile("s_waitcnt vmcnt(4)" ::: "memory");  // tile 0 landed
  __builtin_amdgcn_s_barrier();
  asm volatile("" ::: "memory");

  int sc = 0, ss = 2;
  for (int tt = 0; tt < NT; ++tt) {
    {  // stage tile tt+2 (branchless clamped tail keeps vmcnt exact)
      int ts = tt + 2;
      int ko = (ts < NT ? ts : NT - 1) * BK;
      unsigned short* Lb = lds + ss * SLOT_USH;
      glds16(aS[0] + ko, Lb + dA[0]);
      glds16(aS[1] + ko, Lb + dA[1]);
      glds16(bS[0] + ko, Lb + dB[0]);
      glds16(bS[1] + ko, Lb + dB[1]);
    }
    const unsigned short* Lc = lds + sc * SLOT_USH;
    bf16x8 af[4], bf[4];
#pragma unroll
    for (int mi = 0; mi < 4; ++mi) af[mi] = *(const bf16x8*)&Lc[afo[mi]];
#pragma unroll
    for (int ni = 0; ni < 4; ++ni) bf[ni] = *(const bf16x8*)&Lc[bfo[ni]];
    __builtin_amdgcn_s_setprio(1);
#pragma unroll
    for (int mi = 0; mi < 4; ++mi)
#pragma unroll
      for (int ni = 0; ni < 4; ++ni)
        acc[mi][ni] = __builtin_amdgcn_mfma_f32_16x16x32_bf16(af[mi], bf[ni], acc[mi][ni], 0, 0, 0);
    __builtin_amdgcn_s_setprio(0);
    asm volatile("s_waitcnt vmcnt(4)" ::: "memory");  // tile tt+1 landed
    __builtin_amdgcn_s_barrier();
    asm volatile("" ::: "memory");
    if (++sc == 3) sc = 0;
    if (++ss == 3) ss = 0;
  }

  // epilogue: drain, then LDS-transpose -> coalesced 16B stores
  asm volatile("s_waitcnt vmcnt(0)" ::: "memory");
  __builtin_amdgcn_s_barrier();
  asm volatile("" ::: "memory");
  unsigned short* cb = lds + w * 4096;  // 64x64 bf16 per wave (8 KB)
  float bias[4];
#pragma unroll
  for (int ni = 0; ni < 4; ++ni) bias[ni] = b1[e * HH + n0 + wn + ni * 16 + lm];
#pragma unroll
  for (int mi = 0; mi < 4; ++mi)
#pragma unroll
    for (int ni = 0; ni < 4; ++ni)
#pragma unroll
      for (int rr = 0; rr < 4; ++rr)
        cb[(mi * 16 + lq * 4 + rr) * 64 + ni * 16 + lm] =
            f2bf(fmaxf(acc[mi][ni][rr] + bias[ni], 0.0f));
  asm volatile("s_waitcnt lgkmcnt(0)" ::: "memory");
#pragma unroll
  for (int it = 0; it < 8; ++it) {
    int rr = it * 8 + (l >> 3), chk = l & 7;
    int grow = wm + rr;
    if (m0 + grow < cnt_e) {
      uint4 v = *(const uint4*)&cb[rr * 64 + chk * 8];
      *(uint4*)&hc[(size_t)(base + grow) * HH + n0 + wn + chk * 8] = v;
    }
  }
}

// =====================================================================
// GEMM2: y[z][slot] = rw*(hc_rows @ w2[e] + b2[e] [z==0]); same pipeline.
// Locality decode: XCD q = f&7 <-> expert q; r = f>>3; z sequential per
// XCD; within a z-group, m-fastest n-columns share the 0.5 MB B panel;
// the group's A-set (~4 MB) is near-L2-resident.
// =====================================================================
__global__ __launch_bounds__(256, 3) void gemm2_k(const unsigned short* __restrict__ hc,
                                                  const unsigned short* __restrict__ w2t,
                                                  const float* __restrict__ b2,
                                                  const int* __restrict__ cnt,
                                                  const int* __restrict__ list,
                                                  const int* __restrict__ tmap,
                                                  const int* __restrict__ tstart,
                                                  const float* __restrict__ rw,
                                                  float* __restrict__ ybuf,
                                                  float* __restrict__ out) {
  int q = blockIdx.x & 7, r = blockIdx.x >> 3;   // r in [0,512)
  int z = r >> 8, s = r & 255;
  int mts = s & (MTS - 1), nt = s >> 5;          // m-fastest within n-column
  int tc0 = tstart[q];
  if (tc0 + mts >= tstart[q + 1]) return;
  int ti = tc0 + mts;
  int e = tmap[4 * ti], m0 = tmap[4 * ti + 1], base = tmap[4 * ti + 2];
  int cnt_e = cnt[e];
  int n0 = nt * BN;
  int kb0 = z * (HH / 2);
  constexpr int NT = (HH / 2) / BK;  // 64

  __shared__ __align__(16) unsigned short lds[3 * SLOT_USH];
  __shared__ int slotbuf[BM];
  __shared__ float rwbuf[BM];

  int t = threadIdx.x;
  if (t < BM) {
    int rr = m0 + t;
    int s_ = list[e * BT + (rr < cnt_e ? rr : 0)];
    slotbuf[t] = s_;
    rwbuf[t] = rw[s_];
  }
  __syncthreads();

  int w = t >> 6, l = t & 63, lm = l & 15, lq = l >> 4;
  int wm = (w >> 1) * 64, wn = (w & 1) * 64;

  const unsigned short* aS[2];
  const unsigned short* bS[2];
  int dA[2], dB[2];
#pragma unroll
  for (int j = 0; j < 2; ++j) {
    int row = w * 32 + j * 16 + (l >> 2);
    int sch = ((l & 3) ^ ((row >> 1) & 3)) * 8;
    int gr = base + row; if (gr > SLOTS - 1) gr = SLOTS - 1;  // clamp padded rows
    aS[j] = hc + (size_t)gr * HH + kb0 + sch;
    bS[j] = w2t + (size_t)e * OO * HH + (size_t)(n0 + row) * HH + kb0 + sch;
    dA[j] = w * 1024 + j * 512;
    dB[j] = A_USH + w * 1024 + j * 512;
  }

  int xs = (lq ^ ((lm >> 1) & 3)) * 8;
  int afo[4], bfo[4];
#pragma unroll
  for (int mi = 0; mi < 4; ++mi) afo[mi] = (wm + mi * 16 + lm) * BK + xs;
#pragma unroll
  for (int ni = 0; ni < 4; ++ni) bfo[ni] = A_USH + (wn + ni * 16 + lm) * BK + xs;

  f32x4 acc[4][4];
#pragma unroll
  for (int mi = 0; mi < 4; ++mi)
#pragma unroll
    for (int ni = 0; ni < 4; ++ni) acc[mi][ni] = f32x4{0.f, 0.f, 0.f, 0.f};

#pragma unroll
  for (int p = 0; p < 2; ++p) {
    unsigned short* Lb = lds + p * SLOT_USH;
    glds16(aS[0] + p * BK, Lb + dA[0]);
    glds16(aS[1] + p * BK, Lb + dA[1]);
    glds16(bS[0] + p * BK, Lb + dB[0]);
    glds16(bS[1] + p * BK, Lb + dB[1]);
  }
  asm volatile("s_waitcnt vmcnt(4)" ::: "memory");
  __builtin_amdgcn_s_barrier();
  asm volatile("" ::: "memory");

  int sc = 0, ss = 2;
  for (int tt = 0; tt < NT; ++tt) {
    {
      int ts = tt + 2;
      int ko = (ts < NT ? ts : NT - 1) * BK;
      unsigned short* Lb = lds + ss * SLOT_USH;
      glds16(aS[0] + ko, Lb + dA[0]);
      glds16(aS[1] + ko, Lb + dA[1]);
      glds16(bS[0] + ko, Lb + dB[0]);
      glds16(bS[1] + ko, Lb + dB[1]);
    }
    const unsigned short* Lc = lds + sc * SLOT_USH;
    bf16x8 af[4], bf[4];
#pragma unroll
    for (int mi = 0; mi < 4; ++mi) af[mi] = *(const bf16x8*)&Lc[afo[mi]];
#pragma unroll
    for (int ni = 0; ni < 4; ++ni) bf[ni] = *(const bf16x8*)&Lc[bfo[ni]];
    __builtin_amdgcn_s_setprio(1);
#pragma unroll
    for (int mi = 0; mi < 4; ++mi)
#pragma unroll
      for (int ni = 0; ni < 4; ++ni)
        acc[mi][ni] = __builtin_amdgcn_mfma_f32_16x16x32_bf16(af[mi], bf[ni], acc[mi][ni], 0, 0, 0);
    __builtin_amdgcn_s_setprio(0);
    asm volatile("s_waitcnt vmcnt(4)" ::: "memory");
    __builtin_amdgcn_s_barrier();
    asm volatile("" ::: "memory");
    if (++sc == 3) sc = 0;
    if (++ss == 3) ss = 0;
  }
  asm volatile("s_waitcnt vmcnt(0)" ::: "memory");  // drain clamped tail loads

  bool addb = (z == 0);
  size_t ybase = (size_t)z * SLOTS;
#pragma unroll
  for (int ni = 0; ni < 4; ++ni) {
    int ncol = n0 + wn + ni * 16 + lm;
    float bias = addb ? b2[e * OO + ncol] : 0.0f;
#pragma unroll
    for (int mi = 0; mi < 4; ++mi)
#pragma unroll
      for (int rr = 0; rr < 4; ++rr) {
        int lrow = wm + mi * 16 + lq * 4 + rr;
        if (m0 + lrow < cnt_e) {
          float v = (acc[mi][ni][rr] + bias) * rwbuf[lrow];
          int slot = slotbuf[lrow];
          if (ybuf) ybuf[(ybase + slot) * OO + ncol] = v;
          else      atomicAdd(&out[(size_t)(slot >> 1) * OO + ncol], v);
        }
      }
  }
}

// ---- combine: out[b] = sum_z (y[z][2b] + y[z][2b+1]) ----
__global__ __launch_bounds__(256) void combine_k(const float* __restrict__ y,
                                                 float* __restrict__ out, int nz) {
  int i = blockIdx.x * 256 + threadIdx.x;
  int b = i >> 8, c = i & 255;
  f32x4 acc = {0.f, 0.f, 0.f, 0.f};
  for (int z = 0; z < nz; ++z) {
#pragma unroll
    for (int k = 0; k < 2; ++k) {
      const float4 v = *(const float4*)&y[((size_t)z * SLOTS + 2 * b + k) * OO + c * 4];
      acc[0] += v.x; acc[1] += v.y; acc[2] += v.z; acc[3] += v.w;
    }
  }
  *(f32x4*)&out[(size_t)b * OO + c * 4] = acc;
}

extern "C" void kernel_launch(void* const* d_in, const int* in_sizes, int n_in,
                              void* d_out, int out_size, void* d_ws, size_t ws_size,
                              hipStream_t stream) {
  const float* x  = (const float*)d_in[0];
  const float* gw = (const float*)d_in[1];
  const float* gb = (const float*)d_in[2];
  const float* w1 = (const float*)d_in[3];
  const float* b1 = (const float*)d_in[4];
  const float* w2 = (const float*)d_in[5];
  const float* b2 = (const float*)d_in[6];
  float* out = (float*)d_out;
  char* ws = (char*)d_ws;

  int*            cnt    = (int*)(ws);                          // 32 B
  int*            ntiles = (int*)(ws + 64);
  int*            tmap   = (int*)(ws + 128);                    // 72*16 B
  int*            tstart = (int*)(ws + 2560);                   // 9 ints
  float*          rw     = (float*)(ws + 4096);                 // 32 KB
  int*            list   = (int*)(ws + (64u << 10));            // 128 KB
  unsigned short* xb     = (unsigned short*)(ws + (1u  << 20)); // 8 MB
  unsigned short* w1t    = (unsigned short*)(ws + (9u  << 20)); // 64 MB

  bool roomy = ws_size >= (201u << 20);
  hipMemsetAsync(cnt, 0, 64, stream);

  if (roomy) {
    // w2t gets its own region so cvt(w2) overlaps gemm1; ybuf aliases w1t
    // (w1t dead after fusedB; ybuf live only gemm2->combine).
    unsigned short* w2t = (unsigned short*)(ws + (73u  << 20));  // 64 MB
    unsigned short* hc  = (unsigned short*)(ws + (137u << 20));  // 64 MB
    float*          ybuf = (float*)(ws + (9u << 20));            // alias w1t

    fusedA_k<<<1024 + 8192, 256, 0, stream>>>(x, gw, gb, w1, xb, cnt, list, rw, w1t);
    tilemap_k<<<1, 64, 0, stream>>>(cnt, tmap, ntiles, tstart);
    fusedB_k<<<G1_BLKS + 8192, 256, 0, stream>>>(xb, w1t, b1, cnt, list, tmap, tstart,
                                                 hc, w2, w2t);
    gemm2_k<<<G2_BLKS, 256, 0, stream>>>(hc, w2t, b2, cnt, list, tmap,
                                         tstart, rw, ybuf, out);
    combine_k<<<BT * OO / 1024, 256, 0, stream>>>(ybuf, out, 2);
  } else {
    // tight fallback: serial cvt(w2) overwrites w1t region; atomic gemm2.
    if (ws_size < (137u << 20)) return;
    unsigned short* w2t = w1t;
    unsigned short* hc  = (unsigned short*)(ws + (73u << 20));
    hipMemsetAsync(out, 0, (size_t)BT * OO * sizeof(float), stream);
    fusedA_k<<<1024 + 8192, 256, 0, stream>>>(x, gw, gb, w1, xb, cnt, list, rw, w1t);
    tilemap_k<<<1, 64, 0, stream>>>(cnt, tmap, ntiles, tstart);
    fusedB_k<<<G1_BLKS, 256, 0, stream>>>(xb, w1t, b1, cnt, list, tmap, tstart,
                                          hc, w2, w2t);
    cvt_t_k<<<dim3(HH / 64, OO / 64, EE), 256, 0, stream>>>(w2, w2t, HH, OO);
    gemm2_k<<<G2_BLKS, 256, 0, stream>>>(hc, w2t, b2, cnt, list, tmap,
                                         tstart, rw, nullptr, out);
  }
}

// Round 8
// 638.661 us; speedup vs baseline: 1.0250x; 1.0065x over previous
//
#include <hip/hip_runtime.h>
#include <stdint.h>

typedef short bf16x8 __attribute__((ext_vector_type(8)));
typedef float f32x4  __attribute__((ext_vector_type(4)));

constexpr int BT = 4096;   // tokens
constexpr int DD = 1024;   // model dim
constexpr int OO = 1024;   // output dim
constexpr int EE = 8;      // experts
constexpr int HH = 4096;   // hidden dim
constexpr int SLOTS = 2 * BT;  // 8192

// ---- GEMM geometry: 128x128 tile, BK=32, 2-phase dbuf, 4 blocks/CU ----
constexpr int BM = 128, BN = 128, BK = 32;
constexpr int A_USH = BM * BK;             // 4096 ushorts (8 KB)
constexpr int SLOT_USH = (BM + BN) * BK;   // 8192 ushorts (16 KB)
constexpr int MTS = 32;                    // m-tile slots/expert (covers 4096 tok worst case)
constexpr int G1_BLKS = 8 * 32 * MTS;      // 8192
constexpr int G2_BLKS = 8 * 2 * 8 * MTS;   // 4096

__device__ __forceinline__ unsigned short f2bf(float f) {
  unsigned u = __float_as_uint(f);
  u += 0x7fffu + ((u >> 16) & 1u);   // round-to-nearest-even
  return (unsigned short)(u >> 16);
}

// async 16B global->LDS. LDS dest is wave-uniform base; HW adds lane*16.
__device__ __forceinline__ void glds16(const unsigned short* g, unsigned short* l) {
  __builtin_amdgcn_global_load_lds(
      (const __attribute__((address_space(1))) void*)g,
      (__attribute__((address_space(3))) void*)l, 16, 0, 0);
}

// ------- transpose+convert: 64 rows x 256 cols per block, 16-deep MLP -------
// src fp32 [e][R][C] -> dst bf16 [e][C][R]. All 16 loads issued before any
// use (float4 v[16], statically indexed) so HBM latency overlaps.
__device__ __forceinline__ void cvt_body4(const float* __restrict__ src,
                                          unsigned short* __restrict__ dst,
                                          int R, int C, int e, int r0, int c0, int t,
                                          unsigned short (*tile)[66]) {
  const float* s = src + (size_t)e * R * C;
  unsigned short* d = dst + (size_t)e * R * C;
  float4 v[16];
#pragma unroll
  for (int u = 0; u < 4; ++u)
#pragma unroll
    for (int p = 0; p < 4; ++p) {
      int ch = p * 256 + t;
      int rr = ch >> 4, cc = (ch & 15) << 2;
      v[u * 4 + p] = *(const float4*)&s[(size_t)(r0 + rr) * C + c0 + u * 64 + cc];
    }
#pragma unroll
  for (int u = 0; u < 4; ++u) {
#pragma unroll
    for (int p = 0; p < 4; ++p) {
      int ch = p * 256 + t;
      int rr = ch >> 4, cc = (ch & 15) << 2;
      float4 q = v[u * 4 + p];
      unsigned lo = (unsigned)f2bf(q.x) | ((unsigned)f2bf(q.y) << 16);
      unsigned hi = (unsigned)f2bf(q.z) | ((unsigned)f2bf(q.w) << 16);
      *(uint2*)&tile[rr][cc] = make_uint2(lo, hi);
    }
    __syncthreads();
#pragma unroll
    for (int p = 0; p < 4; ++p) {
      int ch = p * 256 + t;
      int cc = ch >> 4, rr = (ch & 15) << 2;
      unsigned short v0 = tile[rr + 0][cc];
      unsigned short v1 = tile[rr + 1][cc];
      unsigned short v2 = tile[rr + 2][cc];
      unsigned short v3 = tile[rr + 3][cc];
      unsigned lo = (unsigned)v0 | ((unsigned)v1 << 16);
      unsigned hi = (unsigned)v2 | ((unsigned)v3 << 16);
      *(uint2*)&d[(size_t)(c0 + u * 64 + cc) * R + r0 + rr] = make_uint2(lo, hi);
    }
    __syncthreads();
  }
}

// ---------- fusedA: router (blocks 0..1023) + cvt(w1) (blocks 1024..3071) ----------
__global__ __launch_bounds__(256) void fusedA_k(const float* __restrict__ x,
                                                const float* __restrict__ gw,
                                                const float* __restrict__ gb,
                                                const float* __restrict__ w1,
                                                unsigned short* __restrict__ xb,
                                                int* __restrict__ cnt,
                                                int* __restrict__ list,
                                                float* __restrict__ rw,
                                                unsigned short* __restrict__ w1t) {
  __shared__ unsigned short tile[64][66];
  int bid = blockIdx.x;
  if (bid >= 1024) {  // cvt(w1): fp32 [e][1024][4096] -> bf16 [e][4096][1024]
    int idx = bid - 1024;          // [0,2048)
    int e = idx >> 8, rem = idx & 255;
    int r0 = (rem & 15) << 6, c0 = (rem >> 4) << 8;
    cvt_body4(w1, w1t, DD, HH, e, r0, c0, threadIdx.x, tile);
    return;
  }
  int wave = threadIdx.x >> 6, lane = threadIdx.x & 63;
  int b = bid * 4 + wave;
  const float* xrow = x + (size_t)b * DD;
  float acc[8];
#pragma unroll
  for (int e = 0; e < 8; ++e) acc[e] = 0.f;
#pragma unroll
  for (int i = 0; i < 4; ++i) {
    int d0 = i * 256 + lane * 4;
    float4 v = *(const float4*)&xrow[d0];
    unsigned lo = (unsigned)f2bf(v.x) | ((unsigned)f2bf(v.y) << 16);
    unsigned hi = (unsigned)f2bf(v.z) | ((unsigned)f2bf(v.w) << 16);
    *(uint2*)&xb[(size_t)b * DD + d0] = make_uint2(lo, hi);
    const float* g0 = &gw[(size_t)d0 * 8];
    float fv[4] = {v.x, v.y, v.z, v.w};
#pragma unroll
    for (int q = 0; q < 4; ++q) {
      float4 ga = *(const float4*)&g0[q * 8];
      float4 gc = *(const float4*)&g0[q * 8 + 4];
      acc[0] += fv[q] * ga.x; acc[1] += fv[q] * ga.y;
      acc[2] += fv[q] * ga.z; acc[3] += fv[q] * ga.w;
      acc[4] += fv[q] * gc.x; acc[5] += fv[q] * gc.y;
      acc[6] += fv[q] * gc.z; acc[7] += fv[q] * gc.w;
    }
  }
#pragma unroll
  for (int off = 32; off > 0; off >>= 1) {
#pragma unroll
    for (int e = 0; e < 8; ++e) acc[e] += __shfl_down(acc[e], off);
  }
  if (lane == 0) {
    float v[8];
#pragma unroll
    for (int e = 0; e < 8; ++e) v[e] = acc[e] + gb[e];
    int i0 = 0;
#pragma unroll
    for (int e = 1; e < 8; ++e) if (v[e] > v[i0]) i0 = e;
    int i1 = (i0 == 0) ? 1 : 0;
#pragma unroll
    for (int e = 0; e < 8; ++e) if (e != i0 && v[e] > v[i1]) i1 = e;
    float e1 = __expf(v[i1] - v[i0]);
    float inv = 1.0f / (1.0f + e1);
    int p0 = atomicAdd(&cnt[i0], 1);
    list[i0 * BT + p0] = 2 * b;     rw[2 * b]     = inv;
    int p1 = atomicAdd(&cnt[i1], 1);
    list[i1 * BT + p1] = 2 * b + 1; rw[2 * b + 1] = e1 * inv;
  }
}

// ---- tile map: (expert, m0, compacted_base) per 128-row tile + per-expert prefix ----
__global__ void tilemap_k(const int* __restrict__ cnt, int* __restrict__ tmap,
                          int* __restrict__ ntiles, int* __restrict__ tstart) {
  if (threadIdx.x == 0 && blockIdx.x == 0) {
    int t = 0, basewalk = 0;
    for (int e = 0; e < EE; ++e) {
      tstart[e] = t;
      int c = cnt[e];
      for (int m0 = 0; m0 < c; m0 += BM) {
        tmap[4 * t] = e; tmap[4 * t + 1] = m0; tmap[4 * t + 2] = basewalk + m0; ++t;
      }
      basewalk += c;
    }
    tstart[EE] = t;
    *ntiles = t;
  }
}

// standalone cvt (tight-ws fallback only); grid (R/64, C/256, E)
__global__ __launch_bounds__(256) void cvt_t_k(const float* __restrict__ src,
                                               unsigned short* __restrict__ dst,
                                               int R, int C) {
  __shared__ unsigned short tile[64][66];
  cvt_body4(src, dst, R, C, blockIdx.z, blockIdx.x << 6, blockIdx.y << 8,
            threadIdx.x, tile);
}

// =====================================================================
// fusedB: GEMM1 (blocks 0..G1_BLKS-1) + cvt(w2) (blocks G1_BLKS..+2047).
// GEMM1: hc[base+row] = relu(x[tok] @ w1[e] + b1[e]), compacted layout.
// 128x128 tile, BK=32, 2-phase double-buffer (m248 recipe): STAGE(t+1)
// issued BEFORE compute(t), one vmcnt(0)+barrier per tile. 32KB LDS ->
// 4 blocks/CU. XOR chunk swizzle (conflict-free), expert<->XCD affinity
// (q = f&7 <-> expert q, m-fastest within n-column -> B panel L2-hit).
// =====================================================================
__global__ __launch_bounds__(256, 4) void fusedB_k(const unsigned short* __restrict__ xb,
                                                   const unsigned short* __restrict__ w1t,
                                                   const float* __restrict__ b1,
                                                   const int* __restrict__ cnt,
                                                   const int* __restrict__ list,
                                                   const int* __restrict__ tmap,
                                                   const int* __restrict__ tstart,
                                                   unsigned short* __restrict__ hc,
                                                   const float* __restrict__ w2,
                                                   unsigned short* __restrict__ w2t) {
  __shared__ __align__(16) unsigned short lds[2 * SLOT_USH];  // 32 KB
  __shared__ int slotbuf[BM];
  int bid = blockIdx.x;
  if (bid >= G1_BLKS) {  // cvt(w2): fp32 [e][4096][1024] -> bf16 [e][1024][4096]
    int idx = bid - G1_BLKS;       // [0,2048)
    int e = idx >> 8, rem = idx & 255;
    int r0 = (rem & 63) << 6, c0 = (rem >> 6) << 8;
    cvt_body4(w2, w2t, HH, OO, e, r0, c0, threadIdx.x,
              (unsigned short (*)[66])lds);
    return;
  }
  // expert<->XCD affinity decode
  int q = bid & 7, r = bid >> 3;
  int mts = r & (MTS - 1), nt = r >> 5;    // m-fastest within n-column
  int tc0 = tstart[q];
  if (tc0 + mts >= tstart[q + 1]) return;  // beyond this expert's m-tiles
  int ti = tc0 + mts;
  int e = tmap[4 * ti], m0 = tmap[4 * ti + 1], base = tmap[4 * ti + 2];
  int cnt_e = cnt[e];
  int n0 = nt * BN;

  int t = threadIdx.x;
  if (t < BM) {
    int rr = m0 + t;
    slotbuf[t] = list[e * BT + (rr < cnt_e ? rr : 0)];
  }
  __syncthreads();

  int w = t >> 6, l = t & 63, lm = l & 15, lq = l >> 4;
  int wm = (w >> 1) * 64, wn = (w & 1) * 64;

  // staging: 4 x 16B per thread per K-tile; inverse swizzle on GLOBAL source.
  const unsigned short* aS[2];
  const unsigned short* bS[2];
  int dA[2], dB[2];
#pragma unroll
  for (int j = 0; j < 2; ++j) {
    int row = w * 32 + j * 16 + (l >> 2);
    int sch = ((l & 3) ^ ((row >> 1) & 3)) * 8;
    aS[j] = xb + (size_t)(slotbuf[row] >> 1) * DD + sch;
    bS[j] = w1t + (size_t)e * HH * DD + (size_t)(n0 + row) * DD + sch;
    dA[j] = w * 1024 + j * 512;
    dB[j] = A_USH + w * 1024 + j * 512;
  }

  // fragment read offsets with matching swizzle (2-way -> conflict-free)
  int xs = (lq ^ ((lm >> 1) & 3)) * 8;
  int afo[4], bfo[4];
#pragma unroll
  for (int mi = 0; mi < 4; ++mi) afo[mi] = (wm + mi * 16 + lm) * BK + xs;
#pragma unroll
  for (int ni = 0; ni < 4; ++ni) bfo[ni] = A_USH + (wn + ni * 16 + lm) * BK + xs;

  f32x4 acc[4][4];
#pragma unroll
  for (int mi = 0; mi < 4; ++mi)
#pragma unroll
    for (int ni = 0; ni < 4; ++ni) acc[mi][ni] = f32x4{0.f, 0.f, 0.f, 0.f};

  constexpr int NT = DD / BK;  // 32

  // 2-phase prologue: stage tile 0 -> slot 0, full drain
  {
    unsigned short* Lb = lds;
    glds16(aS[0], Lb + dA[0]); glds16(aS[1], Lb + dA[1]);
    glds16(bS[0], Lb + dB[0]); glds16(bS[1], Lb + dB[1]);
  }
  asm volatile("s_waitcnt vmcnt(0)" ::: "memory");
  __builtin_amdgcn_s_barrier();
  asm volatile("" ::: "memory");

  for (int tt = 0; tt < NT; ++tt) {
    {  // STAGE(t+1) into other slot, issued before compute (tail: clamped re-stage)
      int ts = tt + 1;
      int ko = (ts < NT ? ts : NT - 1) * BK;
      unsigned short* Lb = lds + (ts & 1) * SLOT_USH;
      glds16(aS[0] + ko, Lb + dA[0]); glds16(aS[1] + ko, Lb + dA[1]);
      glds16(bS[0] + ko, Lb + dB[0]); glds16(bS[1] + ko, Lb + dB[1]);
    }
    const unsigned short* Lc = lds + (tt & 1) * SLOT_USH;
    bf16x8 af[4], bf[4];
#pragma unroll
    for (int mi = 0; mi < 4; ++mi) af[mi] = *(const bf16x8*)&Lc[afo[mi]];
#pragma unroll
    for (int ni = 0; ni < 4; ++ni) bf[ni] = *(const bf16x8*)&Lc[bfo[ni]];
    __builtin_amdgcn_s_setprio(1);
#pragma unroll
    for (int mi = 0; mi < 4; ++mi)
#pragma unroll
      for (int ni = 0; ni < 4; ++ni)
        acc[mi][ni] = __builtin_amdgcn_mfma_f32_16x16x32_bf16(af[mi], bf[ni], acc[mi][ni], 0, 0, 0);
    __builtin_amdgcn_s_setprio(0);
    asm volatile("s_waitcnt vmcnt(0)" ::: "memory");  // next tile landed
    __builtin_amdgcn_s_barrier();
    asm volatile("" ::: "memory");
  }

  // epilogue: LDS-transpose -> coalesced 16B stores
  unsigned short* cb = lds + w * 4096;  // 64x64 bf16 per wave (8 KB)
  float bias[4];
#pragma unroll
  for (int ni = 0; ni < 4; ++ni) bias[ni] = b1[e * HH + n0 + wn + ni * 16 + lm];
#pragma unroll
  for (int mi = 0; mi < 4; ++mi)
#pragma unroll
    for (int ni = 0; ni < 4; ++ni)
#pragma unroll
      for (int rr = 0; rr < 4; ++rr)
        cb[(mi * 16 + lq * 4 + rr) * 64 + ni * 16 + lm] =
            f2bf(fmaxf(acc[mi][ni][rr] + bias[ni], 0.0f));
  asm volatile("s_waitcnt lgkmcnt(0)" ::: "memory");
#pragma unroll
  for (int it = 0; it < 8; ++it) {
    int rr = it * 8 + (l >> 3), chk = l & 7;
    int grow = wm + rr;
    if (m0 + grow < cnt_e) {
      uint4 v = *(const uint4*)&cb[rr * 64 + chk * 8];
      *(uint4*)&hc[(size_t)(base + grow) * HH + n0 + wn + chk * 8] = v;
    }
  }
}

// =====================================================================
// GEMM2: y[z][slot] = rw*(hc_rows @ w2[e] + b2[e] [z==0]); same 2-phase.
// Affinity: XCD q = f&7 <-> expert q; z sequential per XCD; m-fastest.
// =====================================================================
__global__ __launch_bounds__(256, 4) void gemm2_k(const unsigned short* __restrict__ hc,
                                                  const unsigned short* __restrict__ w2t,
                                                  const float* __restrict__ b2,
                                                  const int* __restrict__ cnt,
                                                  const int* __restrict__ list,
                                                  const int* __restrict__ tmap,
                                                  const int* __restrict__ tstart,
                                                  const float* __restrict__ rw,
                                                  float* __restrict__ ybuf,
                                                  float* __restrict__ out) {
  int q = blockIdx.x & 7, r = blockIdx.x >> 3;   // r in [0,512)
  int z = r >> 8, s = r & 255;
  int mts = s & (MTS - 1), nt = s >> 5;          // m-fastest within n-column
  int tc0 = tstart[q];
  if (tc0 + mts >= tstart[q + 1]) return;
  int ti = tc0 + mts;
  int e = tmap[4 * ti], m0 = tmap[4 * ti + 1], base = tmap[4 * ti + 2];
  int cnt_e = cnt[e];
  int n0 = nt * BN;
  int kb0 = z * (HH / 2);
  constexpr int NT = (HH / 2) / BK;  // 64

  __shared__ __align__(16) unsigned short lds[2 * SLOT_USH];
  __shared__ int slotbuf[BM];
  __shared__ float rwbuf[BM];

  int t = threadIdx.x;
  if (t < BM) {
    int rr = m0 + t;
    int s_ = list[e * BT + (rr < cnt_e ? rr : 0)];
    slotbuf[t] = s_;
    rwbuf[t] = rw[s_];
  }
  __syncthreads();

  int w = t >> 6, l = t & 63, lm = l & 15, lq = l >> 4;
  int wm = (w >> 1) * 64, wn = (w & 1) * 64;

  const unsigned short* aS[2];
  const unsigned short* bS[2];
  int dA[2], dB[2];
#pragma unroll
  for (int j = 0; j < 2; ++j) {
    int row = w * 32 + j * 16 + (l >> 2);
    int sch = ((l & 3) ^ ((row >> 1) & 3)) * 8;
    int gr = base + row; if (gr > SLOTS - 1) gr = SLOTS - 1;  // clamp padded rows
    aS[j] = hc + (size_t)gr * HH + kb0 + sch;
    bS[j] = w2t + (size_t)e * OO * HH + (size_t)(n0 + row) * HH + kb0 + sch;
    dA[j] = w * 1024 + j * 512;
    dB[j] = A_USH + w * 1024 + j * 512;
  }

  int xs = (lq ^ ((lm >> 1) & 3)) * 8;
  int afo[4], bfo[4];
#pragma unroll
  for (int mi = 0; mi < 4; ++mi) afo[mi] = (wm + mi * 16 + lm) * BK + xs;
#pragma unroll
  for (int ni = 0; ni < 4; ++ni) bfo[ni] = A_USH + (wn + ni * 16 + lm) * BK + xs;

  f32x4 acc[4][4];
#pragma unroll
  for (int mi = 0; mi < 4; ++mi)
#pragma unroll
    for (int ni = 0; ni < 4; ++ni) acc[mi][ni] = f32x4{0.f, 0.f, 0.f, 0.f};

  {
    unsigned short* Lb = lds;
    glds16(aS[0], Lb + dA[0]); glds16(aS[1], Lb + dA[1]);
    glds16(bS[0], Lb + dB[0]); glds16(bS[1], Lb + dB[1]);
  }
  asm volatile("s_waitcnt vmcnt(0)" ::: "memory");
  __builtin_amdgcn_s_barrier();
  asm volatile("" ::: "memory");

  for (int tt = 0; tt < NT; ++tt) {
    {
      int ts = tt + 1;
      int ko = (ts < NT ? ts : NT - 1) * BK;
      unsigned short* Lb = lds + (ts & 1) * SLOT_USH;
      glds16(aS[0] + ko, Lb + dA[0]); glds16(aS[1] + ko, Lb + dA[1]);
      glds16(bS[0] + ko, Lb + dB[0]); glds16(bS[1] + ko, Lb + dB[1]);
    }
    const unsigned short* Lc = lds + (tt & 1) * SLOT_USH;
    bf16x8 af[4], bf[4];
#pragma unroll
    for (int mi = 0; mi < 4; ++mi) af[mi] = *(const bf16x8*)&Lc[afo[mi]];
#pragma unroll
    for (int ni = 0; ni < 4; ++ni) bf[ni] = *(const bf16x8*)&Lc[bfo[ni]];
    __builtin_amdgcn_s_setprio(1);
#pragma unroll
    for (int mi = 0; mi < 4; ++mi)
#pragma unroll
      for (int ni = 0; ni < 4; ++ni)
        acc[mi][ni] = __builtin_amdgcn_mfma_f32_16x16x32_bf16(af[mi], bf[ni], acc[mi][ni], 0, 0, 0);
    __builtin_amdgcn_s_setprio(0);
    asm volatile("s_waitcnt vmcnt(0)" ::: "memory");
    __builtin_amdgcn_s_barrier();
    asm volatile("" ::: "memory");
  }

  bool addb = (z == 0);
  size_t ybase = (size_t)z * SLOTS;
#pragma unroll
  for (int ni = 0; ni < 4; ++ni) {
    int ncol = n0 + wn + ni * 16 + lm;
    float bias = addb ? b2[e * OO + ncol] : 0.0f;
#pragma unroll
    for (int mi = 0; mi < 4; ++mi)
#pragma unroll
      for (int rr = 0; rr < 4; ++rr) {
        int lrow = wm + mi * 16 + lq * 4 + rr;
        if (m0 + lrow < cnt_e) {
          float v = (acc[mi][ni][rr] + bias) * rwbuf[lrow];
          int slot = slotbuf[lrow];
          if (ybuf) ybuf[(ybase + slot) * OO + ncol] = v;
          else      atomicAdd(&out[(size_t)(slot >> 1) * OO + ncol], v);
        }
      }
  }
}

// ---- combine: out[b] = sum_z (y[z][2b] + y[z][2b+1]) ----
__global__ __launch_bounds__(256) void combine_k(const float* __restrict__ y,
                                                 float* __restrict__ out, int nz) {
  int i = blockIdx.x * 256 + threadIdx.x;
  int b = i >> 8, c = i & 255;
  f32x4 acc = {0.f, 0.f, 0.f, 0.f};
  for (int z = 0; z < nz; ++z) {
#pragma unroll
    for (int k = 0; k < 2; ++k) {
      const float4 v = *(const float4*)&y[((size_t)z * SLOTS + 2 * b + k) * OO + c * 4];
      acc[0] += v.x; acc[1] += v.y; acc[2] += v.z; acc[3] += v.w;
    }
  }
  *(f32x4*)&out[(size_t)b * OO + c * 4] = acc;
}

extern "C" void kernel_launch(void* const* d_in, const int* in_sizes, int n_in,
                              void* d_out, int out_size, void* d_ws, size_t ws_size,
                              hipStream_t stream) {
  const float* x  = (const float*)d_in[0];
  const float* gw = (const float*)d_in[1];
  const float* gb = (const float*)d_in[2];
  const float* w1 = (const float*)d_in[3];
  const float* b1 = (const float*)d_in[4];
  const float* w2 = (const float*)d_in[5];
  const float* b2 = (const float*)d_in[6];
  float* out = (float*)d_out;
  char* ws = (char*)d_ws;

  int*            cnt    = (int*)(ws);                          // 32 B
  int*            ntiles = (int*)(ws + 64);
  int*            tmap   = (int*)(ws + 128);                    // 72*16 B
  int*            tstart = (int*)(ws + 2560);                   // 9 ints
  float*          rw     = (float*)(ws + 4096);                 // 32 KB
  int*            list   = (int*)(ws + (64u << 10));            // 128 KB
  unsigned short* xb     = (unsigned short*)(ws + (1u  << 20)); // 8 MB
  unsigned short* w1t    = (unsigned short*)(ws + (9u  << 20)); // 64 MB

  bool roomy = ws_size >= (201u << 20);
  hipMemsetAsync(cnt, 0, 64, stream);

  if (roomy) {
    // w2t gets its own region so cvt(w2) overlaps gemm1; ybuf aliases w1t
    // (w1t dead after fusedB; ybuf live only gemm2->combine).
    unsigned short* w2t = (unsigned short*)(ws + (73u  << 20));  // 64 MB
    unsigned short* hc  = (unsigned short*)(ws + (137u << 20));  // 64 MB
    float*          ybuf = (float*)(ws + (9u << 20));            // alias w1t

    fusedA_k<<<1024 + 2048, 256, 0, stream>>>(x, gw, gb, w1, xb, cnt, list, rw, w1t);
    tilemap_k<<<1, 64, 0, stream>>>(cnt, tmap, ntiles, tstart);
    fusedB_k<<<G1_BLKS + 2048, 256, 0, stream>>>(xb, w1t, b1, cnt, list, tmap, tstart,
                                                 hc, w2, w2t);
    gemm2_k<<<G2_BLKS, 256, 0, stream>>>(hc, w2t, b2, cnt, list, tmap,
                                         tstart, rw, ybuf, out);
    combine_k<<<BT * OO / 1024, 256, 0, stream>>>(ybuf, out, 2);
  } else {
    // tight fallback: serial cvt(w2) overwrites w1t region; atomic gemm2.
    if (ws_size < (137u << 20)) return;
    unsigned short* w2t = w1t;
    unsigned short* hc  = (unsigned short*)(ws + (73u << 20));
    hipMemsetAsync(out, 0, (size_t)BT * OO * sizeof(float), stream);
    fusedA_k<<<1024 + 2048, 256, 0, stream>>>(x, gw, gb, w1, xb, cnt, list, rw, w1t);
    tilemap_k<<<1, 64, 0, stream>>>(cnt, tmap, ntiles, tstart);
    fusedB_k<<<G1_BLKS, 256, 0, stream>>>(xb, w1t, b1, cnt, list, tmap, tstart,
                                          hc, w2, w2t);
    cvt_t_k<<<dim3(HH / 64, OO / 256, EE), 256, 0, stream>>>(w2, w2t, HH, OO);
    gemm2_k<<<G2_BLKS, 256, 0, stream>>>(hc, w2t, b2, cnt, list, tmap,
                                         tstart, rw, nullptr, out);
  }
}